// Round 4
// baseline (193.228 us; speedup 1.0000x reference)
//
#include <hip/hip_runtime.h>
#include <hip/hip_bf16.h>
#include <stdint.h>

// NTXentLoss: B=4096, D=512, N=8192, tau=0.07, out = scalar mean loss.
// loss_i = -sim[i, i^B] + M + log( sum_{j != i} exp(sim_ij - M) ),  M = 1/tau
// mean  = M + ( Sum_i log S_i  -  Sum_i pos_i ) / N
//
// R4: revert BK=128 (R3 regression: +4 conflict cyc per ds_read_b128, worse
// latency profile). Keep R2's BK=64 + mod-8 rotation swizzle (0 conflicts) and
// R3's fused finale. NEW: 512-thread blocks, 8 waves x (64x32 C tile),
// acc = 32 AGPR -> total regs <= 128/wave -> 4 waves/SIMD (16 waves/CU),
// doubling resident waves in a latency-stall-bound kernel.

#define N_TOT   8192
#define B_HALF  4096
#define DDIM    512
#define INV_TAU 14.285714285714286f   // 1/0.07 == fixed logsumexp offset M
#define NBLK    2080                  // 64*65/2 upper-triangle 128x128 tiles

typedef __bf16 bf16x8 __attribute__((ext_vector_type(8)));
typedef __bf16 bf16x4 __attribute__((ext_vector_type(4)));
typedef float  floatx4 __attribute__((ext_vector_type(4)));

__device__ __forceinline__ void gl2lds16(const void* g, void* l) {
    __builtin_amdgcn_global_load_lds(
        (const __attribute__((address_space(1))) void*)g,
        (__attribute__((address_space(3))) void*)l, 16, 0, 0);
}

// ---------------- kernel 1: normalize rows, fp32 -> bf16 z; zero accum ------
__global__ __launch_bounds__(256) void knorm(const float* __restrict__ anchor,
                                             const float* __restrict__ positive,
                                             __bf16* __restrict__ z,
                                             float* __restrict__ row_sums,
                                             float* __restrict__ pos_total,
                                             unsigned* __restrict__ counter) {
    const int row  = blockIdx.x * 4 + (threadIdx.x >> 6);
    const int lane = threadIdx.x & 63;
    if (lane == 0) row_sums[row] = 0.0f;
    if (blockIdx.x == 0 && threadIdx.x == 0) { pos_total[0] = 0.0f; counter[0] = 0u; }
    const float* src = (row < B_HALF) ? (anchor + (size_t)row * DDIM)
                                      : (positive + (size_t)(row - B_HALF) * DDIM);
    float4 v0 = ((const float4*)src)[lane];
    float4 v1 = ((const float4*)src)[lane + 64];
    float ss = v0.x*v0.x + v0.y*v0.y + v0.z*v0.z + v0.w*v0.w
             + v1.x*v1.x + v1.y*v1.y + v1.z*v1.z + v1.w*v1.w;
    #pragma unroll
    for (int m = 1; m < 64; m <<= 1) ss += __shfl_xor(ss, m, 64);
    const float inv = 1.0f / fmaxf(sqrtf(ss), 1e-8f);
    bf16x4 o0, o1;
    o0[0] = (__bf16)(v0.x*inv); o0[1] = (__bf16)(v0.y*inv);
    o0[2] = (__bf16)(v0.z*inv); o0[3] = (__bf16)(v0.w*inv);
    o1[0] = (__bf16)(v1.x*inv); o1[1] = (__bf16)(v1.y*inv);
    o1[2] = (__bf16)(v1.z*inv); o1[3] = (__bf16)(v1.w*inv);
    bf16x4* dst = (bf16x4*)(z + (size_t)row * DDIM);
    dst[lane]      = o0;
    dst[lane + 64] = o1;
}

// ---------------- kernel 2: upper-triangle sim tiles + fused everything -----
// 2080 blocks (rt <= ct), 512 threads = 8 waves in 2x4; wave = 64x32 C via
// 4x2 16x16x32 frags (acc 32 AGPR). BK=64: LDS 2 x 16 KB, rotation-swizzled
// mod 8 (conflict-free ds_read_b128; global_load_lds keeps wave-uniform base).
__global__ __launch_bounds__(512, 4) void ksim(const __bf16* __restrict__ z,
                                               float* __restrict__ row_sums,
                                               float* __restrict__ pos_total,
                                               unsigned* __restrict__ counter,
                                               float* __restrict__ out) {
    int rem = blockIdx.x, rt = 0;
    while (rem >= 64 - rt) { rem -= 64 - rt; rt++; }
    const int ct = rt + rem;
    const bool diag = (rt == ct);
    const bool posb = (ct == rt + 32);

    const int r0 = rt * 128, c0 = ct * 128;
    const int tid  = threadIdx.x;
    const int w    = tid >> 6, lane = tid & 63;
    const int quad = lane >> 4, nlo = lane & 15;
    const int wrow = (w >> 2) * 64;     // 2 row-groups
    const int wcol = (w & 3) * 32;      // 4 col-groups

    __shared__ __align__(16) char smem[32768];
    __shared__ float sred[8];
    __shared__ unsigned last_flag;
    char* As = smem;            // 16 KB: 128 rows x 128 B
    char* Bs = smem + 16384;    // 16 KB
    const char* Bbase = diag ? As : Bs;

    floatx4 acc[4][2];
    #pragma unroll
    for (int a = 0; a < 4; a++)
        #pragma unroll
        for (int b = 0; b < 2; b++) acc[a][b] = (floatx4){0.f, 0.f, 0.f, 0.f};

    const int srow = lane >> 3;   // row within an 8-row staging chunk
    const int p    = lane & 7;    // physical 16B chunk within 128B row

    for (int kb = 0; kb < DDIM; kb += 64) {
        #pragma unroll
        for (int it = 0; it < 2; it++) {
            const int c  = w * 2 + it;          // 8-row chunk id, 0..15
            const int rr = c * 8 + srow;        // tile row 0..127
            const int lc = (p - rr) & 7;        // logical chunk stored at phys p
            gl2lds16(z + (size_t)(r0 + rr) * DDIM + kb + lc * 8, As + c * 1024);
            if (!diag)
                gl2lds16(z + (size_t)(c0 + rr) * DDIM + kb + lc * 8, Bs + c * 1024);
        }
        __syncthreads();

        #pragma unroll
        for (int ks = 0; ks < 2; ks++) {
            bf16x8 af[4], bfr[2];
            #pragma unroll
            for (int mi = 0; mi < 4; mi++) {
                const int rr = wrow + mi * 16 + nlo;
                const int pc = (ks * 4 + quad + rr) & 7;
                af[mi] = *(const bf16x8*)(As + rr * 128 + pc * 16);
            }
            #pragma unroll
            for (int ni = 0; ni < 2; ni++) {
                const int rr = wcol + ni * 16 + nlo;
                const int pc = (ks * 4 + quad + rr) & 7;
                bfr[ni] = *(const bf16x8*)(Bbase + rr * 128 + pc * 16);
            }
            #pragma unroll
            for (int mi = 0; mi < 4; mi++)
                #pragma unroll
                for (int ni = 0; ni < 2; ni++)
                    acc[mi][ni] = __builtin_amdgcn_mfma_f32_16x16x32_bf16(
                        af[mi], bfr[ni], acc[mi][ni], 0, 0, 0);
        }
        __syncthreads();
    }

    // epilogue: C/D layout col = lane&15, row = quad*4 + reg
    if (diag) {
        #pragma unroll
        for (int mi = 0; mi < 4; mi++) {
            #pragma unroll
            for (int reg = 0; reg < 4; reg++) {
                const int i = r0 + wrow + mi * 16 + quad * 4 + reg;
                float rs = 0.f;
                #pragma unroll
                for (int ni = 0; ni < 2; ni++) {
                    const int j = c0 + wcol + ni * 16 + nlo;
                    const float e = __expf(acc[mi][ni][reg] * INV_TAU - INV_TAU);
                    rs += (j == i) ? 0.f : e;
                }
                rs += __shfl_xor(rs, 1, 64);
                rs += __shfl_xor(rs, 2, 64);
                rs += __shfl_xor(rs, 4, 64);
                rs += __shfl_xor(rs, 8, 64);
                if (nlo == 0) atomicAdd(&row_sums[i], rs);
            }
        }
    } else {
        float cs[2] = {0.f, 0.f};   // per-lane col partials
        float ppos = 0.f;
        #pragma unroll
        for (int mi = 0; mi < 4; mi++) {
            #pragma unroll
            for (int reg = 0; reg < 4; reg++) {
                const int i = r0 + wrow + mi * 16 + quad * 4 + reg;
                const int ipos = i ^ B_HALF;
                float rs = 0.f;
                #pragma unroll
                for (int ni = 0; ni < 2; ni++) {
                    const int j = c0 + wcol + ni * 16 + nlo;
                    const float sim = acc[mi][ni][reg] * INV_TAU;
                    const float e = __expf(sim - INV_TAU);
                    if (posb && j == ipos) ppos += 2.0f * sim; // pair counted for i and i^B
                    rs += e;
                    cs[ni] += e;
                }
                rs += __shfl_xor(rs, 1, 64);
                rs += __shfl_xor(rs, 2, 64);
                rs += __shfl_xor(rs, 4, 64);
                rs += __shfl_xor(rs, 8, 64);
                if (nlo == 0) atomicAdd(&row_sums[i], rs);
            }
        }
        #pragma unroll
        for (int ni = 0; ni < 2; ni++) {
            float c = cs[ni];
            c += __shfl_xor(c, 16, 64);
            c += __shfl_xor(c, 32, 64);
            if (quad == 0)
                atomicAdd(&row_sums[c0 + wcol + ni * 16 + nlo], c);
        }
        if (posb) {
            #pragma unroll
            for (int m = 1; m < 64; m <<= 1) ppos += __shfl_xor(ppos, m, 64);
            if (lane == 0) atomicAdd(pos_total, ppos);
        }
    }

    // ---- last-block final reduction ----
    __syncthreads();                 // all waves' atomics issued & drained
    if (tid == 0) {
        __threadfence();
        last_flag = (atomicAdd(counter, 1u) == NBLK - 1) ? 1u : 0u;
    }
    __syncthreads();
    if (last_flag) {
        __threadfence();
        float acc2 = 0.f;
        for (int i = tid; i < N_TOT; i += 512)
            acc2 += __logf(atomicAdd(&row_sums[i], 0.0f));   // coherent read
        #pragma unroll
        for (int m = 1; m < 64; m <<= 1) acc2 += __shfl_xor(acc2, m, 64);
        if (lane == 0) sred[w] = acc2;
        __syncthreads();
        if (tid == 0) {
            float logsum = 0.f;
            #pragma unroll
            for (int k = 0; k < 8; k++) logsum += sred[k];
            const float pt = atomicAdd(pos_total, 0.0f);
            out[0] = INV_TAU + (logsum - pt) * (1.0f / (float)N_TOT);
        }
    }
}

extern "C" void kernel_launch(void* const* d_in, const int* in_sizes, int n_in,
                              void* d_out, int out_size, void* d_ws, size_t ws_size,
                              hipStream_t stream) {
    const float* anchor   = (const float*)d_in[0];
    const float* positive = (const float*)d_in[1];
    float* out = (float*)d_out;

    char* ws = (char*)d_ws;
    __bf16*   z         = (__bf16*)ws;                         // 8 MB
    float*    row_sums  = (float*)(ws + 8388608);              // 32 KB
    float*    pos_total = (float*)(ws + 8388608 + 32768);      // 4 B
    unsigned* counter   = (unsigned*)(ws + 8388608 + 32768 + 256);

    knorm<<<N_TOT / 4, 256, 0, stream>>>(anchor, positive, z, row_sums, pos_total, counter);
    ksim<<<NBLK, 512, 0, stream>>>(z, row_sums, pos_total, counter, out);
}

// Round 5
// 164.393 us; speedup vs baseline: 1.1754x; 1.1754x over previous
//
#include <hip/hip_runtime.h>
#include <hip/hip_bf16.h>
#include <stdint.h>

// NTXentLoss: B=4096, D=512, N=8192, tau=0.07, out = scalar mean loss.
// loss_i = -sim[i, i^B] + M + log( sum_{j != i} exp(sim_ij - M) ),  M = 1/tau
// mean  = M + ( Sum_i log S_i  -  Sum_i pos_i ) / N
//
// R5: R2 geometry (2080 upper-tri blocks, 4 waves x 64x64, BK=64) with an
// fp8-e4m3 datapath: z stored as fp8 scaled by 16 (sim = acc/256/tau).
// Halves staging bytes, LDS read bytes, and frag registers; MFMA rate
// unchanged (non-scaled fp8 == bf16 rate). LDS: 64 superrows x 128 B,
// 16-B chunks rotated mod 8 -> ds_read_b64 frag reads are 2-way max (free),
// global_load_lds stays wave-uniform-base contiguous. launch_bounds(256,3)
// targets 3 blocks/CU (total regs <= 170).

#define N_TOT   8192
#define B_HALF  4096
#define DDIM    512
#define INV_TAU 14.285714285714286f       // 1/0.07 == fixed logsumexp offset M
#define SIM_SCALE (INV_TAU / 256.0f)      // z prescaled by 16 -> acc = 256*cos
#define NBLK    2080                      // 64*65/2 upper-triangle 128x128 tiles

typedef float floatx4 __attribute__((ext_vector_type(4)));

__device__ __forceinline__ void gl2lds16(const void* g, void* l) {
    __builtin_amdgcn_global_load_lds(
        (const __attribute__((address_space(1))) void*)g,
        (__attribute__((address_space(3))) void*)l, 16, 0, 0);
}

// ---- kernel 1: normalize rows, fp32 -> fp8 e4m3 (x16); zero accumulators ----
// one wave per row (8 contiguous elements per lane), block = 4 rows
__global__ __launch_bounds__(256) void knorm(const float* __restrict__ anchor,
                                             const float* __restrict__ positive,
                                             uint8_t* __restrict__ z,
                                             float* __restrict__ row_sums,
                                             float* __restrict__ pos_total,
                                             unsigned* __restrict__ counter) {
    const int row  = blockIdx.x * 4 + (threadIdx.x >> 6);
    const int lane = threadIdx.x & 63;
    if (lane == 0) row_sums[row] = 0.0f;
    if (blockIdx.x == 0 && threadIdx.x == 0) { pos_total[0] = 0.0f; counter[0] = 0u; }
    const float* src = (row < B_HALF) ? (anchor + (size_t)row * DDIM)
                                      : (positive + (size_t)(row - B_HALF) * DDIM);
    float4 v0 = ((const float4*)src)[lane * 2];
    float4 v1 = ((const float4*)src)[lane * 2 + 1];
    float ss = v0.x*v0.x + v0.y*v0.y + v0.z*v0.z + v0.w*v0.w
             + v1.x*v1.x + v1.y*v1.y + v1.z*v1.z + v1.w*v1.w;
    #pragma unroll
    for (int m = 1; m < 64; m <<= 1) ss += __shfl_xor(ss, m, 64);
    const float s = 16.0f / fmaxf(sqrtf(ss), 1e-8f);
    int lo = 0, hi = 0;
    lo = __builtin_amdgcn_cvt_pk_fp8_f32(v0.x * s, v0.y * s, lo, false);
    lo = __builtin_amdgcn_cvt_pk_fp8_f32(v0.z * s, v0.w * s, lo, true);
    hi = __builtin_amdgcn_cvt_pk_fp8_f32(v1.x * s, v1.y * s, hi, false);
    hi = __builtin_amdgcn_cvt_pk_fp8_f32(v1.z * s, v1.w * s, hi, true);
    ((int2*)(z + (size_t)row * DDIM))[lane] = make_int2(lo, hi);
}

// ---- kernel 2: upper-triangle sim tiles + fused exp-sum / pos / finale -----
// LDS tile = 128 rows x 64 B fp8 = 64 superrows x 128 B; 16-B chunk at
// logical lchunk = (row&1)*4 + kc stored at phys (lchunk + superrow) & 7.
__global__ __launch_bounds__(256, 3) void ksim(const uint8_t* __restrict__ z,
                                               float* __restrict__ row_sums,
                                               float* __restrict__ pos_total,
                                               unsigned* __restrict__ counter,
                                               float* __restrict__ out) {
    int rem = blockIdx.x, rt = 0;
    while (rem >= 64 - rt) { rem -= 64 - rt; rt++; }
    const int ct = rt + rem;
    const bool diag = (rt == ct);
    const bool posb = (ct == rt + 32);

    const int r0 = rt * 128, c0 = ct * 128;
    const int tid  = threadIdx.x;
    const int w    = tid >> 6, lane = tid & 63;
    const int quad = lane >> 4, nlo = lane & 15;
    const int wrow = (w >> 1) * 64, wcol = (w & 1) * 64;

    __shared__ __align__(16) char smem[16384];
    __shared__ float sred[4];
    __shared__ unsigned last_flag;
    char* As = smem;            // 8 KB
    char* Bs = smem + 8192;     // 8 KB
    const char* Bbase = diag ? As : Bs;

    floatx4 acc[4][4];
    #pragma unroll
    for (int a = 0; a < 4; a++)
        #pragma unroll
        for (int b = 0; b < 4; b++) acc[a][b] = (floatx4){0.f, 0.f, 0.f, 0.f};

    const int ssr = lane >> 3;    // superrow within an 8-superrow staging KB
    const int p   = lane & 7;     // physical 16B chunk within 128B superrow

    for (int kb = 0; kb < DDIM; kb += 64) {
        #pragma unroll
        for (int it = 0; it < 2; it++) {
            const int c   = w * 2 + it;        // KB chunk id, 0..7
            const int sr  = c * 8 + ssr;       // superrow 0..63
            const int lch = (p - sr) & 7;      // logical chunk at phys p
            const int row = sr * 2 + (lch >> 2);
            const int kc  = lch & 3;
            gl2lds16(z + (size_t)(r0 + row) * DDIM + kb + kc * 16, As + c * 1024);
            if (!diag)
                gl2lds16(z + (size_t)(c0 + row) * DDIM + kb + kc * 16, Bs + c * 1024);
        }
        __syncthreads();

        #pragma unroll
        for (int ks = 0; ks < 2; ks++) {
            long af[4], bfr[4];
            #pragma unroll
            for (int mi = 0; mi < 4; mi++) {
                const int r  = wrow + mi * 16 + nlo;
                const int sr = r >> 1;
                const int pc = (((r & 1) * 4 + ks * 2 + (quad >> 1)) + sr) & 7;
                af[mi] = *(const long*)(As + sr * 128 + pc * 16 + (quad & 1) * 8);
            }
            #pragma unroll
            for (int ni = 0; ni < 4; ni++) {
                const int r  = wcol + ni * 16 + nlo;
                const int sr = r >> 1;
                const int pc = (((r & 1) * 4 + ks * 2 + (quad >> 1)) + sr) & 7;
                bfr[ni] = *(const long*)(Bbase + sr * 128 + pc * 16 + (quad & 1) * 8);
            }
            #pragma unroll
            for (int mi = 0; mi < 4; mi++)
                #pragma unroll
                for (int ni = 0; ni < 4; ni++)
                    acc[mi][ni] = __builtin_amdgcn_mfma_f32_16x16x32_fp8_fp8(
                        af[mi], bfr[ni], acc[mi][ni], 0, 0, 0);
        }
        __syncthreads();
    }

    // epilogue: C/D layout col = lane&15, row = quad*4 + reg
    if (diag) {
        #pragma unroll
        for (int mi = 0; mi < 4; mi++) {
            #pragma unroll
            for (int reg = 0; reg < 4; reg++) {
                const int i = r0 + wrow + mi * 16 + quad * 4 + reg;
                float rs = 0.f;
                #pragma unroll
                for (int ni = 0; ni < 4; ni++) {
                    const int j = c0 + wcol + ni * 16 + nlo;
                    const float e = __expf(acc[mi][ni][reg] * SIM_SCALE - INV_TAU);
                    rs += (j == i) ? 0.f : e;
                }
                rs += __shfl_xor(rs, 1, 64);
                rs += __shfl_xor(rs, 2, 64);
                rs += __shfl_xor(rs, 4, 64);
                rs += __shfl_xor(rs, 8, 64);
                if (nlo == 0) atomicAdd(&row_sums[i], rs);
            }
        }
    } else {
        float cs[4] = {0.f, 0.f, 0.f, 0.f};
        float ppos = 0.f;
        #pragma unroll
        for (int mi = 0; mi < 4; mi++) {
            #pragma unroll
            for (int reg = 0; reg < 4; reg++) {
                const int i = r0 + wrow + mi * 16 + quad * 4 + reg;
                const int ipos = i ^ B_HALF;
                float rs = 0.f;
                #pragma unroll
                for (int ni = 0; ni < 4; ni++) {
                    const int j = c0 + wcol + ni * 16 + nlo;
                    const float sim = acc[mi][ni][reg] * SIM_SCALE;
                    const float e = __expf(sim - INV_TAU);
                    if (posb && j == ipos) ppos += 2.0f * sim;
                    rs += e;
                    cs[ni] += e;
                }
                rs += __shfl_xor(rs, 1, 64);
                rs += __shfl_xor(rs, 2, 64);
                rs += __shfl_xor(rs, 4, 64);
                rs += __shfl_xor(rs, 8, 64);
                if (nlo == 0) atomicAdd(&row_sums[i], rs);
            }
        }
        #pragma unroll
        for (int ni = 0; ni < 4; ni++) {
            float c = cs[ni];
            c += __shfl_xor(c, 16, 64);
            c += __shfl_xor(c, 32, 64);
            if (quad == 0)
                atomicAdd(&row_sums[c0 + wcol + ni * 16 + nlo], c);
        }
        if (posb) {
            #pragma unroll
            for (int m = 1; m < 64; m <<= 1) ppos += __shfl_xor(ppos, m, 64);
            if (lane == 0) atomicAdd(pos_total, ppos);
        }
    }

    // ---- last-block final reduction ----
    __syncthreads();
    if (tid == 0) {
        __threadfence();
        last_flag = (atomicAdd(counter, 1u) == NBLK - 1) ? 1u : 0u;
    }
    __syncthreads();
    if (last_flag) {
        __threadfence();
        float acc2 = 0.f;
        for (int i = tid; i < N_TOT; i += 256)
            acc2 += __logf(atomicAdd(&row_sums[i], 0.0f));
        #pragma unroll
        for (int m = 1; m < 64; m <<= 1) acc2 += __shfl_xor(acc2, m, 64);
        if (lane == 0) sred[w] = acc2;
        __syncthreads();
        if (tid == 0) {
            const float logsum = sred[0] + sred[1] + sred[2] + sred[3];
            const float pt = atomicAdd(pos_total, 0.0f);
            out[0] = INV_TAU + (logsum - pt) * (1.0f / (float)N_TOT);
        }
    }
}

extern "C" void kernel_launch(void* const* d_in, const int* in_sizes, int n_in,
                              void* d_out, int out_size, void* d_ws, size_t ws_size,
                              hipStream_t stream) {
    const float* anchor   = (const float*)d_in[0];
    const float* positive = (const float*)d_in[1];
    float* out = (float*)d_out;

    char* ws = (char*)d_ws;
    uint8_t*  z         = (uint8_t*)ws;                        // 8192*512 = 4 MB
    float*    row_sums  = (float*)(ws + 8388608);              // 32 KB
    float*    pos_total = (float*)(ws + 8388608 + 32768);      // 4 B
    unsigned* counter   = (unsigned*)(ws + 8388608 + 32768 + 256);

    knorm<<<N_TOT / 4, 256, 0, stream>>>(anchor, positive, z, row_sums, pos_total, counter);
    ksim<<<NBLK, 256, 0, stream>>>(z, row_sums, pos_total, counter, out);
}

// Round 6
// 164.158 us; speedup vs baseline: 1.1771x; 1.0014x over previous
//
#include <hip/hip_runtime.h>
#include <hip/hip_bf16.h>
#include <stdint.h>

// NTXentLoss: B=4096, D=512, N=8192, tau=0.07, out = scalar mean loss.
// loss_i = -sim[i, i^B] + M + log( sum_{j != i} exp(sim_ij - M) ),  M = 1/tau
// mean  = M + ( Sum_i log S_i  -  Sum_i pos_i ) / N
//
// R6: fp8 datapath with K-PERMUTED global layout so fragment reads are b128.
// z byte layout per row: pos = P*64 + q*16 + s*8  <-  orig k = P*64 + s*32 + q*8
// (P = 64-k group, q = MFMA quad, s = ks parity). A lane (quad q) reads ONE
// b128 covering both ks of a 64-k slab; .x/.y feed the two mfma_..._fp8_fp8.
// LDS: 64 superrows x 128 B, 16-B chunks rotated mod 8 -> b128 reads hit every
// bank at exactly 2-way (free, m136); R5's b64 4-way conflicts eliminated.

#define N_TOT   8192
#define B_HALF  4096
#define DDIM    512
#define INV_TAU 14.285714285714286f       // 1/0.07 == fixed logsumexp offset M
#define SIM_SCALE (INV_TAU / 256.0f)      // z prescaled by 16 -> acc = 256*cos
#define NBLK    2080                      // 64*65/2 upper-triangle 128x128 tiles

typedef float floatx4 __attribute__((ext_vector_type(4)));
typedef long  longx2  __attribute__((ext_vector_type(2)));

__device__ __forceinline__ void gl2lds16(const void* g, void* l) {
    __builtin_amdgcn_global_load_lds(
        (const __attribute__((address_space(1))) void*)g,
        (__attribute__((address_space(3))) void*)l, 16, 0, 0);
}

// ---- kernel 1: normalize rows, fp32 -> fp8 e4m3 (x16), k-permuted store ----
// lane covers orig k [8l, 8l+8); permuted slot = (l>>3)*64 + (l&3)*16 + ((l>>2)&1)*8
__global__ __launch_bounds__(256) void knorm(const float* __restrict__ anchor,
                                             const float* __restrict__ positive,
                                             uint8_t* __restrict__ z,
                                             float* __restrict__ row_sums,
                                             float* __restrict__ pos_total,
                                             unsigned* __restrict__ counter) {
    const int row  = blockIdx.x * 4 + (threadIdx.x >> 6);
    const int lane = threadIdx.x & 63;
    if (lane == 0) row_sums[row] = 0.0f;
    if (blockIdx.x == 0 && threadIdx.x == 0) { pos_total[0] = 0.0f; counter[0] = 0u; }
    const float* src = (row < B_HALF) ? (anchor + (size_t)row * DDIM)
                                      : (positive + (size_t)(row - B_HALF) * DDIM);
    float4 v0 = ((const float4*)src)[lane * 2];
    float4 v1 = ((const float4*)src)[lane * 2 + 1];
    float ss = v0.x*v0.x + v0.y*v0.y + v0.z*v0.z + v0.w*v0.w
             + v1.x*v1.x + v1.y*v1.y + v1.z*v1.z + v1.w*v1.w;
    #pragma unroll
    for (int m = 1; m < 64; m <<= 1) ss += __shfl_xor(ss, m, 64);
    const float s = 16.0f / fmaxf(sqrtf(ss), 1e-8f);
    int lo = 0, hi = 0;
    lo = __builtin_amdgcn_cvt_pk_fp8_f32(v0.x * s, v0.y * s, lo, false);
    lo = __builtin_amdgcn_cvt_pk_fp8_f32(v0.z * s, v0.w * s, lo, true);
    hi = __builtin_amdgcn_cvt_pk_fp8_f32(v1.x * s, v1.y * s, hi, false);
    hi = __builtin_amdgcn_cvt_pk_fp8_f32(v1.z * s, v1.w * s, hi, true);
    const int pos = ((lane >> 3) << 6) + ((lane & 3) << 4) + (((lane >> 2) & 1) << 3);
    *(int2*)(z + (size_t)row * DDIM + pos) = make_int2(lo, hi);
}

// ---- kernel 2: upper-triangle sim tiles + fused exp-sum / pos / finale -----
// 2080 blocks (rt <= ct), 4 waves x 64x64 C, BK=64. LDS tile = 64 superrows
// (2 rows each) x 128 B; chunk lc = (row&1)*4 + q stored at phys (lc+sr)&7.
__global__ __launch_bounds__(256, 3) void ksim(const uint8_t* __restrict__ z,
                                               float* __restrict__ row_sums,
                                               float* __restrict__ pos_total,
                                               unsigned* __restrict__ counter,
                                               float* __restrict__ out) {
    int rem = blockIdx.x, rt = 0;
    while (rem >= 64 - rt) { rem -= 64 - rt; rt++; }
    const int ct = rt + rem;
    const bool diag = (rt == ct);
    const bool posb = (ct == rt + 32);

    const int r0 = rt * 128, c0 = ct * 128;
    const int tid  = threadIdx.x;
    const int w    = tid >> 6, lane = tid & 63;
    const int quad = lane >> 4, nlo = lane & 15;
    const int wrow = (w >> 1) * 64, wcol = (w & 1) * 64;

    __shared__ __align__(16) char smem[16384];
    __shared__ float sred[4];
    __shared__ unsigned last_flag;
    char* As = smem;            // 8 KB
    char* Bs = smem + 8192;     // 8 KB
    const char* Bbase = diag ? As : Bs;

    floatx4 acc[4][4];
    #pragma unroll
    for (int a = 0; a < 4; a++)
        #pragma unroll
        for (int b = 0; b < 4; b++) acc[a][b] = (floatx4){0.f, 0.f, 0.f, 0.f};

    const int ssr = lane >> 3;    // superrow within an 8-superrow staging KB
    const int p   = lane & 7;     // physical 16B chunk within 128B superrow

    for (int kb = 0; kb < DDIM; kb += 64) {
        #pragma unroll
        for (int it = 0; it < 2; it++) {
            const int c   = w * 2 + it;        // KB chunk id, 0..7
            const int sr  = c * 8 + ssr;       // superrow 0..63
            const int lch = (p - sr) & 7;      // logical chunk at phys p
            const int row = sr * 2 + (lch >> 2);
            const int q   = lch & 3;
            gl2lds16(z + (size_t)(r0 + row) * DDIM + kb + q * 16, As + c * 1024);
            if (!diag)
                gl2lds16(z + (size_t)(c0 + row) * DDIM + kb + q * 16, Bs + c * 1024);
        }
        __syncthreads();

        longx2 af[4], bfr[4];
        #pragma unroll
        for (int mi = 0; mi < 4; mi++) {
            const int r  = wrow + mi * 16 + nlo;
            const int sr = r >> 1;
            const int pc = (((r & 1) * 4 + quad) + sr) & 7;
            af[mi] = *(const longx2*)(As + sr * 128 + pc * 16);
        }
        #pragma unroll
        for (int ni = 0; ni < 4; ni++) {
            const int r  = wcol + ni * 16 + nlo;
            const int sr = r >> 1;
            const int pc = (((r & 1) * 4 + quad) + sr) & 7;
            bfr[ni] = *(const longx2*)(Bbase + sr * 128 + pc * 16);
        }
        #pragma unroll
        for (int mi = 0; mi < 4; mi++)
            #pragma unroll
            for (int ni = 0; ni < 4; ni++) {
                acc[mi][ni] = __builtin_amdgcn_mfma_f32_16x16x32_fp8_fp8(
                    af[mi].x, bfr[ni].x, acc[mi][ni], 0, 0, 0);
                acc[mi][ni] = __builtin_amdgcn_mfma_f32_16x16x32_fp8_fp8(
                    af[mi].y, bfr[ni].y, acc[mi][ni], 0, 0, 0);
            }
        __syncthreads();
    }

    // epilogue: C/D layout col = lane&15, row = quad*4 + reg
    if (diag) {
        #pragma unroll
        for (int mi = 0; mi < 4; mi++) {
            #pragma unroll
            for (int reg = 0; reg < 4; reg++) {
                const int i = r0 + wrow + mi * 16 + quad * 4 + reg;
                float rs = 0.f;
                #pragma unroll
                for (int ni = 0; ni < 4; ni++) {
                    const int j = c0 + wcol + ni * 16 + nlo;
                    const float e = __expf(acc[mi][ni][reg] * SIM_SCALE - INV_TAU);
                    rs += (j == i) ? 0.f : e;
                }
                rs += __shfl_xor(rs, 1, 64);
                rs += __shfl_xor(rs, 2, 64);
                rs += __shfl_xor(rs, 4, 64);
                rs += __shfl_xor(rs, 8, 64);
                if (nlo == 0) atomicAdd(&row_sums[i], rs);
            }
        }
    } else {
        float cs[4] = {0.f, 0.f, 0.f, 0.f};
        float ppos = 0.f;
        #pragma unroll
        for (int mi = 0; mi < 4; mi++) {
            #pragma unroll
            for (int reg = 0; reg < 4; reg++) {
                const int i = r0 + wrow + mi * 16 + quad * 4 + reg;
                const int ipos = i ^ B_HALF;
                float rs = 0.f;
                #pragma unroll
                for (int ni = 0; ni < 4; ni++) {
                    const int j = c0 + wcol + ni * 16 + nlo;
                    const float sim = acc[mi][ni][reg] * SIM_SCALE;
                    const float e = __expf(sim - INV_TAU);
                    if (posb && j == ipos) ppos += 2.0f * sim;
                    rs += e;
                    cs[ni] += e;
                }
                rs += __shfl_xor(rs, 1, 64);
                rs += __shfl_xor(rs, 2, 64);
                rs += __shfl_xor(rs, 4, 64);
                rs += __shfl_xor(rs, 8, 64);
                if (nlo == 0) atomicAdd(&row_sums[i], rs);
            }
        }
        #pragma unroll
        for (int ni = 0; ni < 4; ni++) {
            float c = cs[ni];
            c += __shfl_xor(c, 16, 64);
            c += __shfl_xor(c, 32, 64);
            if (quad == 0)
                atomicAdd(&row_sums[c0 + wcol + ni * 16 + nlo], c);
        }
        if (posb) {
            #pragma unroll
            for (int m = 1; m < 64; m <<= 1) ppos += __shfl_xor(ppos, m, 64);
            if (lane == 0) atomicAdd(pos_total, ppos);
        }
    }

    // ---- last-block final reduction ----
    __syncthreads();
    if (tid == 0) {
        __threadfence();
        last_flag = (atomicAdd(counter, 1u) == NBLK - 1) ? 1u : 0u;
    }
    __syncthreads();
    if (last_flag) {
        __threadfence();
        float acc2 = 0.f;
        for (int i = tid; i < N_TOT; i += 256)
            acc2 += __logf(atomicAdd(&row_sums[i], 0.0f));
        #pragma unroll
        for (int m = 1; m < 64; m <<= 1) acc2 += __shfl_xor(acc2, m, 64);
        if (lane == 0) sred[w] = acc2;
        __syncthreads();
        if (tid == 0) {
            const float logsum = sred[0] + sred[1] + sred[2] + sred[3];
            const float pt = atomicAdd(pos_total, 0.0f);
            out[0] = INV_TAU + (logsum - pt) * (1.0f / (float)N_TOT);
        }
    }
}

extern "C" void kernel_launch(void* const* d_in, const int* in_sizes, int n_in,
                              void* d_out, int out_size, void* d_ws, size_t ws_size,
                              hipStream_t stream) {
    const float* anchor   = (const float*)d_in[0];
    const float* positive = (const float*)d_in[1];
    float* out = (float*)d_out;

    char* ws = (char*)d_ws;
    uint8_t*  z         = (uint8_t*)ws;                        // 8192*512 = 4 MB
    float*    row_sums  = (float*)(ws + 8388608);              // 32 KB
    float*    pos_total = (float*)(ws + 8388608 + 32768);      // 4 B
    unsigned* counter   = (unsigned*)(ws + 8388608 + 32768 + 256);

    knorm<<<N_TOT / 4, 256, 0, stream>>>(anchor, positive, z, row_sums, pos_total, counter);
    ksim<<<NBLK, 256, 0, stream>>>(z, row_sums, pos_total, counter, out);
}

// Round 7
// 155.565 us; speedup vs baseline: 1.2421x; 1.0552x over previous
//
#include <hip/hip_runtime.h>
#include <hip/hip_bf16.h>
#include <stdint.h>

// NTXentLoss: B=4096, D=512, N=8192, tau=0.07, out = scalar mean loss.
// loss_i = -sim[i, i^B] + M + log( sum_{j != i} exp(sim_ij - M) ),  M = 1/tau
// mean  = M + ( Sum_i log S_i  -  Sum_i pos_i ) / N
//
// R7: BARRIER-FREE ksim. R6 showed all pipes <13% busy with 0 conflicts ->
// the 2-barrier K-loop structure itself was the stall (vmcnt(0)+s_barrier
// serializing every K-step). LDS gave only 2x reuse/block and fp8 z is 4 MB
// (fits per-XCD L2), so fragments now load DIRECTLY global->VGPR from a
// tile-major z layout written by knorm:
//   chunk(g = row>>4, P = k>>6) is 1 KB at g*8192 + P*1024;
//   byte (row&15)*64 + q*16 + s*8  <-  orig k = P*64 + s*32 + q*8
// => a wave's fragment load is one b128/lane at (nlo*64 + quad*16): the 64
// lanes cover the 1-KB chunk exactly (full-line coalescing). K-loop: 8 slabs
// x (8 coalesced b128 loads + 32 MFMA), register double-buffered, NO
// __syncthreads anywhere before the epilogue.

#define N_TOT   8192
#define B_HALF  4096
#define DDIM    512
#define INV_TAU 14.285714285714286f       // 1/0.07 == fixed logsumexp offset M
#define SIM_SCALE (INV_TAU / 256.0f)      // z prescaled by 16 -> acc = 256*cos
#define NBLK    2080                      // 64*65/2 upper-triangle 128x128 tiles

typedef float floatx4 __attribute__((ext_vector_type(4)));
typedef long  longx2  __attribute__((ext_vector_type(2)));

// ---- kernel 1: normalize rows, fp32 -> fp8 e4m3 (x16), tile-major store ----
// one wave per row; lane l covers orig k [8l, 8l+8):
//   P = l>>3, q = l&3, s = (l>>2)&1; dest = g*8192 + P*1024 + r16*64 + q*16 + s*8
__global__ __launch_bounds__(256) void knorm(const float* __restrict__ anchor,
                                             const float* __restrict__ positive,
                                             uint8_t* __restrict__ z,
                                             float* __restrict__ row_sums,
                                             float* __restrict__ pos_total,
                                             unsigned* __restrict__ counter) {
    const int row  = blockIdx.x * 4 + (threadIdx.x >> 6);
    const int lane = threadIdx.x & 63;
    if (lane == 0) row_sums[row] = 0.0f;
    if (blockIdx.x == 0 && threadIdx.x == 0) { pos_total[0] = 0.0f; counter[0] = 0u; }
    const float* src = (row < B_HALF) ? (anchor + (size_t)row * DDIM)
                                      : (positive + (size_t)(row - B_HALF) * DDIM);
    float4 v0 = ((const float4*)src)[lane * 2];
    float4 v1 = ((const float4*)src)[lane * 2 + 1];
    float ss = v0.x*v0.x + v0.y*v0.y + v0.z*v0.z + v0.w*v0.w
             + v1.x*v1.x + v1.y*v1.y + v1.z*v1.z + v1.w*v1.w;
    #pragma unroll
    for (int m = 1; m < 64; m <<= 1) ss += __shfl_xor(ss, m, 64);
    const float s = 16.0f / fmaxf(sqrtf(ss), 1e-8f);
    int lo = 0, hi = 0;
    lo = __builtin_amdgcn_cvt_pk_fp8_f32(v0.x * s, v0.y * s, lo, false);
    lo = __builtin_amdgcn_cvt_pk_fp8_f32(v0.z * s, v0.w * s, lo, true);
    hi = __builtin_amdgcn_cvt_pk_fp8_f32(v1.x * s, v1.y * s, hi, false);
    hi = __builtin_amdgcn_cvt_pk_fp8_f32(v1.z * s, v1.w * s, hi, true);
    const int g   = row >> 4, r16 = row & 15;
    const int P   = lane >> 3, q = lane & 3, sp = (lane >> 2) & 1;
    *(int2*)(z + (size_t)g * 8192 + P * 1024 + r16 * 64 + q * 16 + sp * 8) =
        make_int2(lo, hi);
}

// ---- kernel 2: upper-triangle sim tiles, barrier-free, fused finale --------
__global__ __launch_bounds__(256, 3) void ksim(const uint8_t* __restrict__ z,
                                               float* __restrict__ row_sums,
                                               float* __restrict__ pos_total,
                                               unsigned* __restrict__ counter,
                                               float* __restrict__ out) {
    int rem = blockIdx.x, rt = 0;
    while (rem >= 64 - rt) { rem -= 64 - rt; rt++; }
    const int ct = rt + rem;
    const bool diag = (rt == ct);
    const bool posb = (ct == rt + 32);

    const int r0 = rt * 128, c0 = ct * 128;
    const int tid  = threadIdx.x;
    const int w    = tid >> 6, lane = tid & 63;
    const int quad = lane >> 4, nlo = lane & 15;
    const int wrow = (w >> 1) * 64, wcol = (w & 1) * 64;

    __shared__ float sred[4];
    __shared__ unsigned last_flag;

    // fragment base pointers: row-group g = rt*8 + (w>>1)*4 + mi, etc.
    const uint8_t* abase = z + (size_t)(rt * 8 + (w >> 1) * 4) * 8192
                             + nlo * 64 + quad * 16;
    const uint8_t* bbase = z + (size_t)(ct * 8 + (w & 1) * 4) * 8192
                             + nlo * 64 + quad * 16;

    floatx4 acc[4][4];
    #pragma unroll
    for (int a = 0; a < 4; a++)
        #pragma unroll
        for (int b = 0; b < 4; b++) acc[a][b] = (floatx4){0.f, 0.f, 0.f, 0.f};

    longx2 a0[4], b0[4], a1[4], b1[4];

    auto ld = [&](longx2* A, longx2* Bv, int P) {
        #pragma unroll
        for (int t = 0; t < 4; t++) {
            A[t]  = *(const longx2*)(abase + (size_t)t * 8192 + P * 1024);
            Bv[t] = *(const longx2*)(bbase + (size_t)t * 8192 + P * 1024);
        }
    };
    auto fm = [&](const longx2* A, const longx2* Bv) {
        #pragma unroll
        for (int mi = 0; mi < 4; mi++)
            #pragma unroll
            for (int ni = 0; ni < 4; ni++) {
                acc[mi][ni] = __builtin_amdgcn_mfma_f32_16x16x32_fp8_fp8(
                    A[mi].x, Bv[ni].x, acc[mi][ni], 0, 0, 0);
                acc[mi][ni] = __builtin_amdgcn_mfma_f32_16x16x32_fp8_fp8(
                    A[mi].y, Bv[ni].y, acc[mi][ni], 0, 0, 0);
            }
    };

    ld(a0, b0, 0);
    #pragma unroll
    for (int P = 0; P < 8; P += 2) {
        if (P + 1 < 8) ld(a1, b1, P + 1);
        fm(a0, b0);
        if (P + 2 < 8) ld(a0, b0, P + 2);
        fm(a1, b1);
    }

    // epilogue: C/D layout col = lane&15, row = quad*4 + reg
    if (diag) {
        #pragma unroll
        for (int mi = 0; mi < 4; mi++) {
            #pragma unroll
            for (int reg = 0; reg < 4; reg++) {
                const int i = r0 + wrow + mi * 16 + quad * 4 + reg;
                float rs = 0.f;
                #pragma unroll
                for (int ni = 0; ni < 4; ni++) {
                    const int j = c0 + wcol + ni * 16 + nlo;
                    const float e = __expf(acc[mi][ni][reg] * SIM_SCALE - INV_TAU);
                    rs += (j == i) ? 0.f : e;
                }
                rs += __shfl_xor(rs, 1, 64);
                rs += __shfl_xor(rs, 2, 64);
                rs += __shfl_xor(rs, 4, 64);
                rs += __shfl_xor(rs, 8, 64);
                if (nlo == 0) atomicAdd(&row_sums[i], rs);
            }
        }
    } else {
        float cs[4] = {0.f, 0.f, 0.f, 0.f};
        float ppos = 0.f;
        #pragma unroll
        for (int mi = 0; mi < 4; mi++) {
            #pragma unroll
            for (int reg = 0; reg < 4; reg++) {
                const int i = r0 + wrow + mi * 16 + quad * 4 + reg;
                const int ipos = i ^ B_HALF;
                float rs = 0.f;
                #pragma unroll
                for (int ni = 0; ni < 4; ni++) {
                    const int j = c0 + wcol + ni * 16 + nlo;
                    const float sim = acc[mi][ni][reg] * SIM_SCALE;
                    const float e = __expf(sim - INV_TAU);
                    if (posb && j == ipos) ppos += 2.0f * sim;
                    rs += e;
                    cs[ni] += e;
                }
                rs += __shfl_xor(rs, 1, 64);
                rs += __shfl_xor(rs, 2, 64);
                rs += __shfl_xor(rs, 4, 64);
                rs += __shfl_xor(rs, 8, 64);
                if (nlo == 0) atomicAdd(&row_sums[i], rs);
            }
        }
        #pragma unroll
        for (int ni = 0; ni < 4; ni++) {
            float c = cs[ni];
            c += __shfl_xor(c, 16, 64);
            c += __shfl_xor(c, 32, 64);
            if (quad == 0)
                atomicAdd(&row_sums[c0 + wcol + ni * 16 + nlo], c);
        }
        if (posb) {
            #pragma unroll
            for (int m = 1; m < 64; m <<= 1) ppos += __shfl_xor(ppos, m, 64);
            if (lane == 0) atomicAdd(pos_total, ppos);
        }
    }

    // ---- last-block final reduction ----
    __syncthreads();
    if (tid == 0) {
        __threadfence();
        last_flag = (atomicAdd(counter, 1u) == NBLK - 1) ? 1u : 0u;
    }
    __syncthreads();
    if (last_flag) {
        __threadfence();
        float acc2 = 0.f;
        #pragma unroll 4
        for (int i = tid; i < N_TOT; i += 256)
            acc2 += __logf(atomicAdd(&row_sums[i], 0.0f));
        #pragma unroll
        for (int m = 1; m < 64; m <<= 1) acc2 += __shfl_xor(acc2, m, 64);
        if (lane == 0) sred[w] = acc2;
        __syncthreads();
        if (tid == 0) {
            const float logsum = sred[0] + sred[1] + sred[2] + sred[3];
            const float pt = atomicAdd(pos_total, 0.0f);
            out[0] = INV_TAU + (logsum - pt) * (1.0f / (float)N_TOT);
        }
    }
}

extern "C" void kernel_launch(void* const* d_in, const int* in_sizes, int n_in,
                              void* d_out, int out_size, void* d_ws, size_t ws_size,
                              hipStream_t stream) {
    const float* anchor   = (const float*)d_in[0];
    const float* positive = (const float*)d_in[1];
    float* out = (float*)d_out;

    char* ws = (char*)d_ws;
    uint8_t*  z         = (uint8_t*)ws;                        // 8192*512 = 4 MB
    float*    row_sums  = (float*)(ws + 8388608);              // 32 KB
    float*    pos_total = (float*)(ws + 8388608 + 32768);      // 4 B
    unsigned* counter   = (unsigned*)(ws + 8388608 + 32768 + 256);

    knorm<<<N_TOT / 4, 256, 0, stream>>>(anchor, positive, z, row_sums, pos_total, counter);
    ksim<<<NBLK, 256, 0, stream>>>(z, row_sums, pos_total, counter, out);
}